// Round 4
// baseline (1560.981 us; speedup 1.0000x reference)
//
#include <hip/hip_runtime.h>

#define KNN   8
#define GD    40
#define NCELL (GD*GD*GD)
#define EPSW  1e-8f
#define BIGF  3.4e38f

typedef unsigned long long u64;
typedef unsigned int u32;

// Init key: d2 part = BIGF bits (0x7F7FFFFF), idx part all-ones.
#define KEY_INIT 0x7F7FFFFFFFFFFFFFull

// Sorted-descending top-8 of u64 keys (key = (f32bits(d2c)<<32)|idx).
// key compare = lexicographic (d2, idx): exactly the reference's top_k order.
__device__ __forceinline__ void ins8(u64 key, u64 bk[KNN]) {
    if (key < bk[0]) {
        bk[0] = key;
#pragma unroll
        for (int t = 0; t < KNN - 1; t++) {
            if (bk[t] < bk[t + 1]) { u64 tmp = bk[t]; bk[t] = bk[t + 1]; bk[t + 1] = tmp; }
        }
    }
}

__device__ __forceinline__ int cell1(float x, float lo, float inv) {
    int c = (int)floorf((x - lo) * inv);
    return min(max(c, 0), GD - 1);
}
__device__ __forceinline__ bool inbox(float x, float y, float z, const float* B) {
    return x >= B[0] && x <= B[3] && y >= B[1] && y <= B[4] && z >= B[2] && z <= B[5];
}

// ---- K1: per-axis mean/sigma over refs -> grid box (mean +- 3.2 sigma) ----
__global__ __launch_bounds__(256) void bounds_kern(const float* __restrict__ r, int M,
                                                   float* __restrict__ B) {
    __shared__ float red[256][6];
    int tid = threadIdx.x;
    float s0=0,s1=0,s2=0,s3=0,s4=0,s5=0;
    for (int j = tid; j < M; j += 256) {
        float x=r[3*j], y=r[3*j+1], z=r[3*j+2];
        s0+=x; s1+=y; s2+=z; s3+=x*x; s4+=y*y; s5+=z*z;
    }
    red[tid][0]=s0; red[tid][1]=s1; red[tid][2]=s2;
    red[tid][3]=s3; red[tid][4]=s4; red[tid][5]=s5;
    __syncthreads();
    for (int off = 128; off > 0; off >>= 1) {
        if (tid < off)
            for (int k = 0; k < 6; k++) red[tid][k] += red[tid+off][k];
        __syncthreads();
    }
    if (tid == 0) {
        float mc = BIGF;
        for (int a = 0; a < 3; a++) {
            float mean = red[0][a] / M;
            float var = fmaxf(red[0][3+a]/M - mean*mean, 1e-6f);
            float sd = sqrtf(var);
            float lo = mean - 3.2f*sd, hi = mean + 3.2f*sd;
            B[a] = lo; B[3+a] = hi;
            float c = (hi - lo) / GD;
            B[6+a] = c; B[9+a] = 1.0f / c;
            mc = fminf(mc, c);
        }
        B[12] = mc;
    }
}

// ---- K2: count refs & queries per cell (outliers/far excluded) ----
__global__ __launch_bounds__(256) void count_kern(const float* __restrict__ r,
        const float* __restrict__ q, int M, int N, const float* __restrict__ B,
        int* __restrict__ rcnt, int* __restrict__ qcnt) {
    int t = blockIdx.x*256 + threadIdx.x;
    if (t < M) {
        float x=r[3*t], y=r[3*t+1], z=r[3*t+2];
        if (inbox(x,y,z,B)) {
            int c = (cell1(z,B[2],B[11])*GD + cell1(y,B[1],B[10]))*GD + cell1(x,B[0],B[9]);
            atomicAdd(&rcnt[c], 1);
        }
    }
    if (t < N) {
        float x=q[3*t], y=q[3*t+1], z=q[3*t+2];
        if (inbox(x,y,z,B)) {
            int c = (cell1(z,B[2],B[11])*GD + cell1(y,B[1],B[10]))*GD + cell1(x,B[0],B[9]);
            atomicAdd(&qcnt[c], 1);
        }
    }
}

// ---- K3: exclusive prefix. block0: rcnt->roff,rpos. block1: qcnt->qpos + qtot ----
__global__ __launch_bounds__(1024) void prefix_kern(const int* __restrict__ rcnt,
        int* __restrict__ roff, int* __restrict__ rpos,
        const int* __restrict__ qcnt, int* __restrict__ qpos, int* __restrict__ cnts) {
    __shared__ int lds[1024];
    const int CH = (NCELL + 1023) / 1024;
    int tid = threadIdx.x;
    const int* src = (blockIdx.x == 0) ? rcnt : qcnt;
    int base = tid * CH;
    int sum = 0;
    for (int i = 0; i < CH; i++) { int c = base + i; if (c < NCELL) sum += src[c]; }
    lds[tid] = sum; __syncthreads();
    for (int off = 1; off < 1024; off <<= 1) {
        int v = (tid >= off) ? lds[tid - off] : 0;
        __syncthreads();
        lds[tid] += v;
        __syncthreads();
    }
    int run = (tid == 0) ? 0 : lds[tid - 1];
    for (int i = 0; i < CH; i++) {
        int c = base + i;
        if (c < NCELL) {
            if (blockIdx.x == 0) { roff[c] = run; rpos[c] = run; }
            else                 { qpos[c] = run; }
            run += src[c];
        }
    }
    if (blockIdx.x == 1 && tid == 1023) cnts[0] = lds[1023];  // qtot
}

// ---- K4: scatter refs (grid lists / outlier list) and queries (sorted / far) ----
__global__ __launch_bounds__(256) void scatter_kern(const float* __restrict__ r,
        const float* __restrict__ q, int M, int N, const float* __restrict__ B,
        int* __restrict__ rpos, int* __restrict__ qpos,
        float4* __restrict__ rpts, int* __restrict__ rid,
        float4* __restrict__ opts, int* __restrict__ oid,
        int* __restrict__ qlist, int* __restrict__ qfar, int* __restrict__ cnts) {
    int t = blockIdx.x*256 + threadIdx.x;
    if (t < M) {
        float x=r[3*t], y=r[3*t+1], z=r[3*t+2];
        float r2 = x*x + y*y + z*z;               // same fp32 formula as reference path
        if (inbox(x,y,z,B)) {
            int c = (cell1(z,B[2],B[11])*GD + cell1(y,B[1],B[10]))*GD + cell1(x,B[0],B[9]);
            int s = atomicAdd(&rpos[c], 1);
            rpts[s] = make_float4(x,y,z,r2); rid[s] = t;
        } else {
            int s = atomicAdd(&cnts[1], 1);
            opts[s] = make_float4(x,y,z,r2); oid[s] = t;
        }
    }
    if (t < N) {
        float x=q[3*t], y=q[3*t+1], z=q[3*t+2];
        if (inbox(x,y,z,B)) {
            int c = (cell1(z,B[2],B[11])*GD + cell1(y,B[1],B[10]))*GD + cell1(x,B[0],B[9]);
            qlist[atomicAdd(&qpos[c], 1)] = t;
        } else {
            qfar[atomicAdd(&cnts[2], 1)] = t;
        }
    }
}

// ---- K5: grid KNN for inner queries (cell-sorted order) + IDW epilogue ----
__global__ __launch_bounds__(64) void knn_grid(const float* __restrict__ q,
        const float* __restrict__ f, const float4* __restrict__ rpts,
        const int* __restrict__ rid, const int* __restrict__ roff,
        const int* __restrict__ rcnt, const float4* __restrict__ opts,
        const int* __restrict__ oid, const int* __restrict__ qlist,
        const int* __restrict__ cnts, const float* __restrict__ B,
        float* __restrict__ out) {
    int t = blockIdx.x*64 + threadIdx.x;
    int qtot = cnts[0];
    if (t >= qtot) return;
    int qi = qlist[t];
    float qx=q[3*qi], qy=q[3*qi+1], qz=q[3*qi+2];
    float q2 = qx*qx + qy*qy + qz*qz;
    u64 bk[KNN];
#pragma unroll
    for (int k = 0; k < KNN; k++) bk[k] = KEY_INIT;
    float thr = BIGF;
    float lox=B[0], loy=B[1], loz=B[2];
    float cw=B[6], chh=B[7], cdd=B[8];
    float mincell = B[12];
    int hx = cell1(qx,lox,B[9]), hy = cell1(qy,loy,B[10]), hz = cell1(qz,loz,B[11]);

    for (int rho = 0; rho < GD; rho++) {
        if (rho >= 2) {  // remaining cells are at Chebyshev >= rho -> dist >= (rho-1)*mincell
            float b = (rho - 1) * mincell;
            if (b*b > thr*1.001f + 0.01f) break;   // slack >> fp error of d2 formula
        }
        int zlo = max(hz-rho, 0), zhi = min(hz+rho, GD-1);
        for (int cz = zlo; cz <= zhi; cz++) {
            int rdz = abs(cz - hz);
            int ylo = max(hy-rho, 0), yhi = min(hy+rho, GD-1);
            for (int cy = ylo; cy <= yhi; cy++) {
                int rdy = abs(cy - hy);
                int step = (rdz == rho || rdy == rho) ? 1 : 2*rho;
                for (int cx = hx - rho; cx <= hx + rho; cx += step) {
                    if (cx < 0 || cx >= GD) continue;
                    int c = (cz*GD + cy)*GD + cx;
                    int n = rcnt[c];
                    if (n == 0) continue;
                    float bx = lox + cx*cw;
                    float by = loy + cy*chh;
                    float bz = loz + cz*cdd;
                    float dx = fmaxf(fmaxf(bx - qx, qx - (bx + cw)), 0.f);
                    float dy = fmaxf(fmaxf(by - qy, qy - (by + chh)), 0.f);
                    float dz = fmaxf(fmaxf(bz - qz, qz - (bz + cdd)), 0.f);
                    float md = dx*dx + dy*dy + dz*dz;
                    if (md > thr*1.001f + 0.01f) continue;
                    int s0 = roff[c];
                    for (int s = s0; s < s0 + n; s++) {
                        float4 p = rpts[s];
                        float d2 = (q2 + p.w) - 2.0f*(qx*p.x + qy*p.y + qz*p.z);
                        float d2c = fmaxf(d2, 0.0f);   // matches reference max(d2,0)
                        if (d2c <= thr) {
                            ins8(((u64)__float_as_uint(d2c) << 32) | (u32)rid[s], bk);
                            thr = __uint_as_float((u32)(bk[0] >> 32));
                        }
                    }
                }
            }
        }
    }
    // outlier refs: always scanned (no pruning) -> every ref examined or provably far
    int on = cnts[1];
    for (int s = 0; s < on; s++) {
        float4 p = opts[s];
        float d2 = (q2 + p.w) - 2.0f*(qx*p.x + qy*p.y + qz*p.z);
        float d2c = fmaxf(d2, 0.0f);
        if (d2c <= thr) {
            ins8(((u64)__float_as_uint(d2c) << 32) | (u32)oid[s], bk);
            thr = __uint_as_float((u32)(bk[0] >> 32));
        }
    }
    float wsum=0.f, ox=0.f, oy=0.f, oz=0.f;
#pragma unroll
    for (int k = 0; k < KNN; k++) {
        float d2c = __uint_as_float((u32)(bk[k] >> 32));
        int j = (int)(u32)bk[k];
        float w = 1.0f / (d2c + EPSW);
        wsum += w;
        ox += w*f[3*j]; oy += w*f[3*j+1]; oz += w*f[3*j+2];
    }
    float invw = 1.0f / wsum;
    out[3*qi] = ox*invw; out[3*qi+1] = oy*invw; out[3*qi+2] = oz*invw;
}

// ---- K6: brute-force wave-per-query for far queries, shuffle-butterfly merge ----
__global__ __launch_bounds__(256) void knn_far(const float* __restrict__ q,
        const float* __restrict__ r, const float* __restrict__ f,
        const int* __restrict__ qfar, const int* __restrict__ cnts,
        float* __restrict__ out, int M) {
    int gw = (blockIdx.x*256 + threadIdx.x) >> 6;
    int lane = threadIdx.x & 63;
    int nw = (gridDim.x*256) >> 6;
    int nf = cnts[2];
    for (int w = gw; w < nf; w += nw) {
        int qi = qfar[w];
        float qx=q[3*qi], qy=q[3*qi+1], qz=q[3*qi+2];
        float q2 = qx*qx + qy*qy + qz*qz;
        u64 bk[KNN];
#pragma unroll
        for (int k = 0; k < KNN; k++) bk[k] = KEY_INIT;
        float thr = BIGF;
        for (int j = lane; j < M; j += 64) {
            float rx=r[3*j], ry=r[3*j+1], rz=r[3*j+2];
            float r2 = rx*rx + ry*ry + rz*rz;
            float d2 = (q2 + r2) - 2.0f*(qx*rx + qy*ry + qz*rz);
            float d2c = fmaxf(d2, 0.0f);
            if (d2c <= thr) {
                ins8(((u64)__float_as_uint(d2c) << 32) | (u32)j, bk);
                thr = __uint_as_float((u32)(bk[0] >> 32));
            }
        }
#pragma unroll
        for (int d = 1; d < 64; d <<= 1) {
            u64 ok[KNN];
#pragma unroll
            for (int k = 0; k < KNN; k++)
                ok[k] = (u64)__shfl_xor((long long)bk[k], d, 64);
#pragma unroll
            for (int k = 0; k < KNN; k++) ins8(ok[k], bk);
        }
        if (lane == 0) {
            float wsum=0.f, ox=0.f, oy=0.f, oz=0.f;
#pragma unroll
            for (int k = 0; k < KNN; k++) {
                float d2c = __uint_as_float((u32)(bk[k] >> 32));
                int j = (int)(u32)bk[k];
                float wt = 1.0f / (d2c + EPSW);
                wsum += wt;
                ox += wt*f[3*j]; oy += wt*f[3*j+1]; oz += wt*f[3*j+2];
            }
            float invw = 1.0f / wsum;
            out[3*qi] = ox*invw; out[3*qi+1] = oy*invw; out[3*qi+2] = oz*invw;
        }
    }
}

// ---------- fallback (ws too small): fused single-pass brute force ----------
__global__ __launch_bounds__(256) void knn_fused(const float* __restrict__ q,
        const float* __restrict__ r, const float* __restrict__ f,
        float* __restrict__ out, int N, int M) {
    __shared__ float4 lds[2048];
    int qi = blockIdx.x*256 + threadIdx.x;
    float qx=0,qy=0,qz=0,q2=0;
    if (qi < N) { qx=q[3*qi]; qy=q[3*qi+1]; qz=q[3*qi+2]; q2=qx*qx+qy*qy+qz*qz; }
    u64 bk[KNN];
#pragma unroll
    for (int k = 0; k < KNN; k++) bk[k] = KEY_INIT;
    float thr = BIGF;
    for (int tb = 0; tb < M; tb += 2048) {
        int cnt = min(2048, M - tb);
        for (int i = threadIdx.x; i < cnt; i += 256) {
            int j = tb + i;
            float rx=r[3*j], ry=r[3*j+1], rz=r[3*j+2];
            lds[i] = make_float4(rx, ry, rz, rx*rx+ry*ry+rz*rz);
        }
        __syncthreads();
        for (int i = 0; i < cnt; i++) {
            float4 p = lds[i];
            float d2 = (q2 + p.w) - 2.0f*(qx*p.x + qy*p.y + qz*p.z);
            float d2c = fmaxf(d2, 0.0f);
            if (d2c <= thr) {
                ins8(((u64)__float_as_uint(d2c) << 32) | (u32)(tb + i), bk);
                thr = __uint_as_float((u32)(bk[0] >> 32));
            }
        }
        __syncthreads();
    }
    if (qi < N) {
        float wsum=0.f, ox=0.f, oy=0.f, oz=0.f;
#pragma unroll
        for (int k = 0; k < KNN; k++) {
            float d2c = __uint_as_float((u32)(bk[k] >> 32));
            int j = (int)(u32)bk[k];
            float w = 1.0f / (d2c + EPSW);
            wsum += w;
            ox += w*f[3*j]; oy += w*f[3*j+1]; oz += w*f[3*j+2];
        }
        float invw = 1.0f / wsum;
        out[3*qi] = ox*invw; out[3*qi+1] = oy*invw; out[3*qi+2] = oz*invw;
    }
}

extern "C" void kernel_launch(void* const* d_in, const int* in_sizes, int n_in,
                              void* d_out, int out_size, void* d_ws, size_t ws_size,
                              hipStream_t stream) {
    const float* q = (const float*)d_in[0];
    const float* r = (const float*)d_in[1];
    const float* f = (const float*)d_in[2];
    float* out = (float*)d_out;
    int N = in_sizes[0] / 3;
    int M = in_sizes[1] / 3;

    size_t off = 0;
    auto alloc = [&](size_t bytes) { size_t o = off; off += (bytes + 15) & ~(size_t)15; return o; };
    size_t oB    = alloc(64);
    size_t oCnt  = alloc(16);                 // [qtot, ocnt, qfcnt]
    size_t oRcnt = alloc((size_t)NCELL*4);
    size_t oQcnt = alloc((size_t)NCELL*4);
    size_t oRoff = alloc((size_t)NCELL*4);
    size_t oRpos = alloc((size_t)NCELL*4);
    size_t oQpos = alloc((size_t)NCELL*4);
    size_t oRp   = alloc((size_t)M*16);
    size_t oRid  = alloc((size_t)M*4);
    size_t oOp   = alloc((size_t)M*16);
    size_t oOid  = alloc((size_t)M*4);
    size_t oQl   = alloc((size_t)N*4);
    size_t oQf   = alloc((size_t)N*4);

    if (off > ws_size) {
        knn_fused<<<(N+255)/256, 256, 0, stream>>>(q, r, f, out, N, M);
        return;
    }
    char* ws = (char*)d_ws;
    float*  B    = (float*)(ws + oB);
    int*    cnts = (int*)(ws + oCnt);
    int*    rcnt = (int*)(ws + oRcnt);
    int*    qcnt = (int*)(ws + oQcnt);
    int*    roff = (int*)(ws + oRoff);
    int*    rpos = (int*)(ws + oRpos);
    int*    qpos = (int*)(ws + oQpos);
    float4* rpts = (float4*)(ws + oRp);
    int*    rid  = (int*)(ws + oRid);
    float4* opts = (float4*)(ws + oOp);
    int*    oid  = (int*)(ws + oOid);
    int*    qlist= (int*)(ws + oQl);
    int*    qfar = (int*)(ws + oQf);

    // zero counters + both count arrays (contiguous region)
    hipMemsetAsync(ws + oCnt, 0, (oQcnt + (size_t)NCELL*4) - oCnt, stream);
    bounds_kern<<<1, 256, 0, stream>>>(r, M, B);
    int gcnt = (max(N, M) + 255) / 256;
    count_kern<<<gcnt, 256, 0, stream>>>(r, q, M, N, B, rcnt, qcnt);
    prefix_kern<<<2, 1024, 0, stream>>>(rcnt, roff, rpos, qcnt, qpos, cnts);
    scatter_kern<<<gcnt, 256, 0, stream>>>(r, q, M, N, B, rpos, qpos,
                                           rpts, rid, opts, oid, qlist, qfar, cnts);
    knn_grid<<<(N+63)/64, 64, 0, stream>>>(q, f, rpts, rid, roff, rcnt,
                                           opts, oid, qlist, cnts, B, out);
    knn_far<<<64, 256, 0, stream>>>(q, r, f, qfar, cnts, out, M);
}

// Round 5
// 783.964 us; speedup vs baseline: 1.9911x; 1.9911x over previous
//
#include <hip/hip_runtime.h>

#define KNN   8
#define NB    2048
#define RMAXF 80.0f
#define EPSW  1e-8f
#define BIGF  3.4e38f

typedef unsigned long long u64;
typedef unsigned int u32;

#define KEY_INIT 0x7F7FFFFFFFFFFFFFull

// Sorted-descending top-8 of u64 keys (key = (f32bits(d2c)<<32)|idx).
// Lexicographic (d2, idx) == reference top_k order. Proven R4.
__device__ __forceinline__ void ins8(u64 key, u64 bk[KNN]) {
    if (key < bk[0]) {
        bk[0] = key;
#pragma unroll
        for (int t = 0; t < KNN - 1; t++) {
            if (bk[t] < bk[t + 1]) { u64 tmp = bk[t]; bk[t] = bk[t + 1]; bk[t + 1] = tmp; }
        }
    }
}

// ---- K1: histogram of ref radii into NB bins ----
__global__ __launch_bounds__(256) void hist_kern(const float* __restrict__ r, int M,
                                                 int* __restrict__ hist) {
    int j = blockIdx.x * 256 + threadIdx.x;
    if (j >= M) return;
    float x = r[3*j], y = r[3*j+1], z = r[3*j+2];
    float R = sqrtf(x*x + y*y + z*z);
    int b = min(NB - 1, max(0, (int)(R * (NB / RMAXF))));
    atomicAdd(&hist[b], 1);
}

// ---- K2: exclusive prefix over NB bins (single block; R4-proven pattern) ----
__global__ __launch_bounds__(1024) void prefix2(const int* __restrict__ hist,
                                                int* __restrict__ off, int* __restrict__ pos) {
    __shared__ int lds[1024];
    const int CH = NB / 1024;  // 2
    int tid = threadIdx.x;
    int base = tid * CH;
    int sum = 0;
    for (int i = 0; i < CH; i++) sum += hist[base + i];
    lds[tid] = sum; __syncthreads();
    for (int o = 1; o < 1024; o <<= 1) {
        int v = (tid >= o) ? lds[tid - o] : 0;
        __syncthreads();
        lds[tid] += v;
        __syncthreads();
    }
    int run = (tid == 0) ? 0 : lds[tid - 1];
    for (int i = 0; i < CH; i++) { off[base + i] = run; pos[base + i] = run; run += hist[base + i]; }
    if (tid == 1023) off[NB] = lds[1023];
}

// ---- K3: scatter refs into radius-sorted order (order within bin arbitrary) ----
__global__ __launch_bounds__(256) void scatter2(const float* __restrict__ r, int M,
                                                int* __restrict__ pos,
                                                float4* __restrict__ rp, int* __restrict__ rix) {
    int j = blockIdx.x * 256 + threadIdx.x;
    if (j >= M) return;
    float x = r[3*j], y = r[3*j+1], z = r[3*j+2];
    float r2 = x*x + y*y + z*z;            // same fp32 r2 as reference path
    float R = sqrtf(r2);
    int b = min(NB - 1, max(0, (int)(R * (NB / RMAXF))));
    int s = atomicAdd(&pos[b], 1);
    rp[s] = make_float4(x, y, z, r2);
    rix[s] = j;
}

// ---- K4: wave-per-query annulus KNN + butterfly merge + IDW ----
__global__ __launch_bounds__(256) void knn_ann(const float* __restrict__ q,
        const float* __restrict__ f, const float4* __restrict__ rp,
        const int* __restrict__ rix, const int* __restrict__ off,
        float* __restrict__ out, int N, int M) {
    int w = (blockIdx.x * 256 + threadIdx.x) >> 6;   // global wave id = query id
    int lane = threadIdx.x & 63;
    if (w >= N) return;
    float qx = q[3*w], qy = q[3*w+1], qz = q[3*w+2];
    float q2 = qx*qx + qy*qy + qz*qz;
    float Rq = sqrtf(q2);
    const float binv = NB / RMAXF;

    // 8 radius-rank neighbors -> upper bound on 8th-NN distance.
    int bq = min(NB - 1, max(0, (int)(Rq * binv)));
    int p = off[bq];
    p = min(max(p, 0), M - KNN);
    float thr0 = 0.f;
#pragma unroll
    for (int t = 0; t < KNN; t++) {
        float4 pp = rp[p + t];
        float d2 = (q2 + pp.w) - 2.0f * (qx*pp.x + qy*pp.y + qz*pp.z);
        thr0 = fmaxf(thr0, fmaxf(d2, 0.0f));
    }
    // annulus half-width; slack >> fp cancellation error of the d2 formula
    float s = sqrtf(thr0) * 1.001f + 0.01f;
    int blo = max(0, (int)((Rq - s) * binv));
    int bhi = min(NB - 1, (int)((Rq + s) * binv));
    int lo = off[blo], hi = off[bhi + 1];

    u64 bk[KNN];
#pragma unroll
    for (int k = 0; k < KNN; k++) bk[k] = KEY_INIT;
    float thr = BIGF;
    for (int j = lo + lane; j < hi; j += 64) {
        float4 pp = rp[j];
        float d2 = (q2 + pp.w) - 2.0f * (qx*pp.x + qy*pp.y + qz*pp.z);
        float d2c = fmaxf(d2, 0.0f);       // matches reference max(d2, 0)
        if (d2c <= thr) {
            ins8(((u64)__float_as_uint(d2c) << 32) | (u32)rix[j], bk);
            thr = __uint_as_float((u32)(bk[0] >> 32));
        }
    }
    // butterfly merge across the wave (proven in R4 knn_far)
#pragma unroll
    for (int d = 1; d < 64; d <<= 1) {
        u64 ok[KNN];
#pragma unroll
        for (int k = 0; k < KNN; k++)
            ok[k] = (u64)__shfl_xor((long long)bk[k], d, 64);
#pragma unroll
        for (int k = 0; k < KNN; k++) ins8(ok[k], bk);
    }
    if (lane == 0) {
        float wsum = 0.f, ox = 0.f, oy = 0.f, oz = 0.f;
#pragma unroll
        for (int k = 0; k < KNN; k++) {
            float d2c = __uint_as_float((u32)(bk[k] >> 32));
            int j = (int)(u32)bk[k];
            float wt = 1.0f / (d2c + EPSW);
            wsum += wt;
            ox += wt * f[3*j]; oy += wt * f[3*j+1]; oz += wt * f[3*j+2];
        }
        float invw = 1.0f / wsum;
        out[3*w] = ox * invw; out[3*w+1] = oy * invw; out[3*w+2] = oz * invw;
    }
}

// ---------- fallback (ws too small): fused single-pass brute force ----------
__global__ __launch_bounds__(256) void knn_fused(const float* __restrict__ q,
        const float* __restrict__ r, const float* __restrict__ f,
        float* __restrict__ out, int N, int M) {
    __shared__ float4 lds[2048];
    int qi = blockIdx.x * 256 + threadIdx.x;
    float qx = 0, qy = 0, qz = 0, q2 = 0;
    if (qi < N) { qx = q[3*qi]; qy = q[3*qi+1]; qz = q[3*qi+2]; q2 = qx*qx+qy*qy+qz*qz; }
    u64 bk[KNN];
#pragma unroll
    for (int k = 0; k < KNN; k++) bk[k] = KEY_INIT;
    float thr = BIGF;
    for (int tb = 0; tb < M; tb += 2048) {
        int cnt = min(2048, M - tb);
        for (int i = threadIdx.x; i < cnt; i += 256) {
            int j = tb + i;
            float rx = r[3*j], ry = r[3*j+1], rz = r[3*j+2];
            lds[i] = make_float4(rx, ry, rz, rx*rx + ry*ry + rz*rz);
        }
        __syncthreads();
        for (int i = 0; i < cnt; i++) {
            float4 p = lds[i];
            float d2 = (q2 + p.w) - 2.0f * (qx*p.x + qy*p.y + qz*p.z);
            float d2c = fmaxf(d2, 0.0f);
            if (d2c <= thr) {
                ins8(((u64)__float_as_uint(d2c) << 32) | (u32)(tb + i), bk);
                thr = __uint_as_float((u32)(bk[0] >> 32));
            }
        }
        __syncthreads();
    }
    if (qi < N) {
        float wsum = 0.f, ox = 0.f, oy = 0.f, oz = 0.f;
#pragma unroll
        for (int k = 0; k < KNN; k++) {
            float d2c = __uint_as_float((u32)(bk[k] >> 32));
            int j = (int)(u32)bk[k];
            float wt = 1.0f / (d2c + EPSW);
            wsum += wt;
            ox += wt * f[3*j]; oy += wt * f[3*j+1]; oz += wt * f[3*j+2];
        }
        float invw = 1.0f / wsum;
        out[3*qi] = ox*invw; out[3*qi+1] = oy*invw; out[3*qi+2] = oz*invw;
    }
}

extern "C" void kernel_launch(void* const* d_in, const int* in_sizes, int n_in,
                              void* d_out, int out_size, void* d_ws, size_t ws_size,
                              hipStream_t stream) {
    const float* q = (const float*)d_in[0];
    const float* r = (const float*)d_in[1];
    const float* f = (const float*)d_in[2];
    float* out = (float*)d_out;
    int N = in_sizes[0] / 3;
    int M = in_sizes[1] / 3;

    size_t offb = 0;
    auto alloc = [&](size_t bytes) { size_t o = offb; offb += (bytes + 15) & ~(size_t)15; return o; };
    size_t oHist = alloc((size_t)NB * 4);
    size_t oOff  = alloc((size_t)(NB + 1) * 4);
    size_t oPos  = alloc((size_t)NB * 4);
    size_t oRp   = alloc((size_t)M * 16);
    size_t oRix  = alloc((size_t)M * 4);

    if (offb > ws_size || M < KNN) {
        knn_fused<<<(N + 255) / 256, 256, 0, stream>>>(q, r, f, out, N, M);
        return;
    }
    char* ws = (char*)d_ws;
    int*    hist = (int*)(ws + oHist);
    int*    off  = (int*)(ws + oOff);
    int*    pos  = (int*)(ws + oPos);
    float4* rp   = (float4*)(ws + oRp);
    int*    rix  = (int*)(ws + oRix);

    hipMemsetAsync(hist, 0, (size_t)NB * 4, stream);
    int gm = (M + 255) / 256;
    hist_kern<<<gm, 256, 0, stream>>>(r, M, hist);
    prefix2<<<1, 1024, 0, stream>>>(hist, off, pos);
    scatter2<<<gm, 256, 0, stream>>>(r, M, pos, rp, rix);
    knn_ann<<<(N + 3) / 4, 256, 0, stream>>>(q, f, rp, rix, off, out, N, M);
}

// Round 6
// 681.050 us; speedup vs baseline: 2.2920x; 1.1511x over previous
//
#include <hip/hip_runtime.h>

#define KNN    8
#define GD     32
#define NCELL  (GD*GD*GD)
#define NBX    2048
#define XLO    (-80.0f)
#define XBINV  (NBX / 160.0f)
#define EPSW   1e-8f
#define BIGF   3.4e38f

typedef unsigned long long u64;
typedef unsigned int u32;

#define KEY_INIT 0x7F7FFFFFFFFFFFFFull

// Sorted-descending top-8 of u64 keys (key = (f32bits(d2c)<<32)|idx).
// Lexicographic (d2, idx) == reference top_k order. Proven R4/R5.
__device__ __forceinline__ void ins8(u64 key, u64 bk[KNN]) {
    if (key < bk[0]) {
        bk[0] = key;
#pragma unroll
        for (int t = 0; t < KNN - 1; t++) {
            if (bk[t] < bk[t + 1]) { u64 tmp = bk[t]; bk[t] = bk[t + 1]; bk[t + 1] = tmp; }
        }
    }
}

__device__ __forceinline__ void merge_wave(u64 bk[KNN]) {
#pragma unroll
    for (int d = 1; d < 64; d <<= 1) {
        u64 ok[KNN];
#pragma unroll
        for (int k = 0; k < KNN; k++)
            ok[k] = (u64)__shfl_xor((long long)bk[k], d, 64);
#pragma unroll
        for (int k = 0; k < KNN; k++) ins8(ok[k], bk);
    }
}

__device__ __forceinline__ int cell1(float x, float lo, float inv) {
    int c = (int)floorf((x - lo) * inv);
    return min(max(c, 0), GD - 1);
}
__device__ __forceinline__ int xbin(float x) {
    int b = (int)((x - XLO) * XBINV);
    return min(max(b, 0), NBX - 1);
}

// ---- K1: per-axis mean/sigma over refs -> grid box (mean +- 3.2 sigma). R4-proven. ----
__global__ __launch_bounds__(256) void bounds_kern(const float* __restrict__ r, int M,
                                                   float* __restrict__ B) {
    __shared__ float red[256][6];
    int tid = threadIdx.x;
    float s0=0,s1=0,s2=0,s3=0,s4=0,s5=0;
    for (int j = tid; j < M; j += 256) {
        float x=r[3*j], y=r[3*j+1], z=r[3*j+2];
        s0+=x; s1+=y; s2+=z; s3+=x*x; s4+=y*y; s5+=z*z;
    }
    red[tid][0]=s0; red[tid][1]=s1; red[tid][2]=s2;
    red[tid][3]=s3; red[tid][4]=s4; red[tid][5]=s5;
    __syncthreads();
    for (int off = 128; off > 0; off >>= 1) {
        if (tid < off)
            for (int k = 0; k < 6; k++) red[tid][k] += red[tid+off][k];
        __syncthreads();
    }
    if (tid == 0) {
        for (int a = 0; a < 3; a++) {
            float mean = red[0][a] / M;
            float var = fmaxf(red[0][3+a]/M - mean*mean, 1e-6f);
            float sd = sqrtf(var);
            float lo = mean - 3.2f*sd, hi = mean + 3.2f*sd;
            B[a] = lo; B[3+a] = hi;
            float c = (hi - lo) / GD;
            B[6+a] = c; B[9+a] = 1.0f / c;
        }
    }
}

// ---- K2: count refs per cell (clamped; ALL refs) + per x-bin ----
__global__ __launch_bounds__(256) void count2_kern(const float* __restrict__ r, int M,
        const float* __restrict__ B, int* __restrict__ rcnt, int* __restrict__ hist) {
    int t = blockIdx.x*256 + threadIdx.x;
    if (t >= M) return;
    float x=r[3*t], y=r[3*t+1], z=r[3*t+2];
    int c = (cell1(z,B[2],B[11])*GD + cell1(y,B[1],B[10]))*GD + cell1(x,B[0],B[9]);
    atomicAdd(&rcnt[c], 1);
    atomicAdd(&hist[xbin(x)], 1);
}

// ---- K3: exclusive prefix. block0: rcnt(32768)->roff,rpos. block1: hist(2048)->xoff,xpos ----
__global__ __launch_bounds__(1024) void prefix_both(const int* __restrict__ rcnt,
        int* __restrict__ roff, int* __restrict__ rpos,
        const int* __restrict__ hist, int* __restrict__ xoff, int* __restrict__ xpos) {
    __shared__ int lds[1024];
    int tid = threadIdx.x;
    int n = (blockIdx.x == 0) ? NCELL : NBX;
    const int* src = (blockIdx.x == 0) ? rcnt : hist;
    int CH = n / 1024;
    int base = tid * CH;
    int sum = 0;
    for (int i = 0; i < CH; i++) sum += src[base + i];
    lds[tid] = sum; __syncthreads();
    for (int o = 1; o < 1024; o <<= 1) {
        int v = (tid >= o) ? lds[tid - o] : 0;
        __syncthreads();
        lds[tid] += v;
        __syncthreads();
    }
    int run = (tid == 0) ? 0 : lds[tid - 1];
    for (int i = 0; i < CH; i++) {
        int c = base + i;
        if (blockIdx.x == 0) { roff[c] = run; rpos[c] = run; }
        else                 { xoff[c] = run; xpos[c] = run; }
        run += src[c];
    }
    if (blockIdx.x == 1 && tid == 1023) xoff[NBX] = lds[1023];
}

// ---- K4: scatter refs into cell-sorted copy (coords only) + x-sorted copy (coords+id) ----
__global__ __launch_bounds__(256) void scatter2_kern(const float* __restrict__ r, int M,
        const float* __restrict__ B, int* __restrict__ rpos, int* __restrict__ xpos,
        float4* __restrict__ rpc, float4* __restrict__ rpx, int* __restrict__ rixx) {
    int t = blockIdx.x*256 + threadIdx.x;
    if (t >= M) return;
    float x=r[3*t], y=r[3*t+1], z=r[3*t+2];
    float r2 = x*x + y*y + z*z;               // same fp32 r2 as reference path
    int c = (cell1(z,B[2],B[11])*GD + cell1(y,B[1],B[10]))*GD + cell1(x,B[0],B[9]);
    int s = atomicAdd(&rpos[c], 1);
    rpc[s] = make_float4(x, y, z, r2);
    int b = xbin(x);
    int s2 = atomicAdd(&xpos[b], 1);
    rpx[s2] = make_float4(x, y, z, r2);
    rixx[s2] = t;
}

// ---- K5: wave-per-query: phase A 27-cell seed -> thr0; phase B x-slab complete scan ----
__global__ __launch_bounds__(256) void knn_x(const float* __restrict__ q,
        const float* __restrict__ f, const float4* __restrict__ rpc,
        const int* __restrict__ roff, const int* __restrict__ rcnt,
        const float4* __restrict__ rpx, const int* __restrict__ rixx,
        const int* __restrict__ xoff, const float* __restrict__ B,
        float* __restrict__ out, int N, int M) {
    int w = (blockIdx.x * 256 + threadIdx.x) >> 6;
    int lane = threadIdx.x & 63;
    if (w >= N) return;
    float qx = q[3*w], qy = q[3*w+1], qz = q[3*w+2];
    float q2 = qx*qx + qy*qy + qz*qz;

    // ---- phase A: top-8 over the 27-cell neighborhood (lanes scan disjoint slots) ----
    int hx = cell1(qx, B[0], B[9]), hy = cell1(qy, B[1], B[10]), hz = cell1(qz, B[2], B[11]);
    u64 bk[KNN];
#pragma unroll
    for (int k = 0; k < KNN; k++) bk[k] = KEY_INIT;
    for (int dz = -1; dz <= 1; dz++) {
        int cz = hz + dz;
        if ((unsigned)cz >= GD) continue;
        for (int dy = -1; dy <= 1; dy++) {
            int cy = hy + dy;
            if ((unsigned)cy >= GD) continue;
            for (int dx = -1; dx <= 1; dx++) {
                int cx = hx + dx;
                if ((unsigned)cx >= GD) continue;
                int c = (cz*GD + cy)*GD + cx;
                int n = rcnt[c], s0 = roff[c];      // wave-uniform -> scalar/broadcast
                for (int i = lane; i < n; i += 64) {
                    float4 p = rpc[s0 + i];
                    float d2 = (q2 + p.w) - 2.0f*(qx*p.x + qy*p.y + qz*p.z);
                    float d2c = fmaxf(d2, 0.0f);
                    ins8(((u64)__float_as_uint(d2c) << 32) | (u32)(s0 + i), bk);
                }
            }
        }
    }
    merge_wave(bk);                                  // all lanes -> identical top-8
    float thr0 = __uint_as_float((u32)(bk[0] >> 32)); // 8th-smallest of >=8 distinct refs, or BIGF

    // ---- phase B: complete scan of the x-slab |x - qx| <= s ----
    int lo, hi;
    if (thr0 > BIGF * 0.5f) {                        // <8 seeds found: full scan (rare tail)
        lo = 0; hi = M;
    } else {
        float s = sqrtf(thr0) * 1.001f + 0.05f;      // slack >> fp cancellation error
        lo = xoff[xbin(qx - s)];
        hi = xoff[xbin(qx + s) + 1];
    }
#pragma unroll
    for (int k = 0; k < KNN; k++) bk[k] = KEY_INIT;
    float thr = thr0;                                // valid filter: true top-8 all have d2c <= thr0
    for (int j = lo + lane; j < hi; j += 64) {
        float4 p = rpx[j];
        float d2 = (q2 + p.w) - 2.0f*(qx*p.x + qy*p.y + qz*p.z);
        float d2c = fmaxf(d2, 0.0f);                 // matches reference max(d2, 0)
        if (d2c <= thr) {
            ins8(((u64)__float_as_uint(d2c) << 32) | (u32)rixx[j], bk);
            thr = fminf(thr, __uint_as_float((u32)(bk[0] >> 32)));
        }
    }
    merge_wave(bk);
    if (lane == 0) {
        float wsum = 0.f, ox = 0.f, oy = 0.f, oz = 0.f;
#pragma unroll
        for (int k = 0; k < KNN; k++) {
            float d2c = __uint_as_float((u32)(bk[k] >> 32));
            int j = (int)(u32)bk[k];
            float wt = 1.0f / (d2c + EPSW);
            wsum += wt;
            ox += wt*f[3*j]; oy += wt*f[3*j+1]; oz += wt*f[3*j+2];
        }
        float invw = 1.0f / wsum;
        out[3*w] = ox*invw; out[3*w+1] = oy*invw; out[3*w+2] = oz*invw;
    }
}

// ---------- fallback (ws too small): fused single-pass brute force ----------
__global__ __launch_bounds__(256) void knn_fused(const float* __restrict__ q,
        const float* __restrict__ r, const float* __restrict__ f,
        float* __restrict__ out, int N, int M) {
    __shared__ float4 lds[2048];
    int qi = blockIdx.x * 256 + threadIdx.x;
    float qx = 0, qy = 0, qz = 0, q2 = 0;
    if (qi < N) { qx = q[3*qi]; qy = q[3*qi+1]; qz = q[3*qi+2]; q2 = qx*qx+qy*qy+qz*qz; }
    u64 bk[KNN];
#pragma unroll
    for (int k = 0; k < KNN; k++) bk[k] = KEY_INIT;
    float thr = BIGF;
    for (int tb = 0; tb < M; tb += 2048) {
        int cnt = min(2048, M - tb);
        for (int i = threadIdx.x; i < cnt; i += 256) {
            int j = tb + i;
            float rx = r[3*j], ry = r[3*j+1], rz = r[3*j+2];
            lds[i] = make_float4(rx, ry, rz, rx*rx + ry*ry + rz*rz);
        }
        __syncthreads();
        for (int i = 0; i < cnt; i++) {
            float4 p = lds[i];
            float d2 = (q2 + p.w) - 2.0f * (qx*p.x + qy*p.y + qz*p.z);
            float d2c = fmaxf(d2, 0.0f);
            if (d2c <= thr) {
                ins8(((u64)__float_as_uint(d2c) << 32) | (u32)(tb + i), bk);
                thr = __uint_as_float((u32)(bk[0] >> 32));
            }
        }
        __syncthreads();
    }
    if (qi < N) {
        float wsum = 0.f, ox = 0.f, oy = 0.f, oz = 0.f;
#pragma unroll
        for (int k = 0; k < KNN; k++) {
            float d2c = __uint_as_float((u32)(bk[k] >> 32));
            int j = (int)(u32)bk[k];
            float wt = 1.0f / (d2c + EPSW);
            wsum += wt;
            ox += wt*f[3*j]; oy += wt*f[3*j+1]; oz += wt*f[3*j+2];
        }
        float invw = 1.0f / wsum;
        out[3*qi] = ox*invw; out[3*qi+1] = oy*invw; out[3*qi+2] = oz*invw;
    }
}

extern "C" void kernel_launch(void* const* d_in, const int* in_sizes, int n_in,
                              void* d_out, int out_size, void* d_ws, size_t ws_size,
                              hipStream_t stream) {
    const float* q = (const float*)d_in[0];
    const float* r = (const float*)d_in[1];
    const float* f = (const float*)d_in[2];
    float* out = (float*)d_out;
    int N = in_sizes[0] / 3;
    int M = in_sizes[1] / 3;

    size_t offb = 0;
    auto alloc = [&](size_t bytes) { size_t o = offb; offb += (bytes + 15) & ~(size_t)15; return o; };
    size_t oB    = alloc(64);
    size_t oRcnt = alloc((size_t)NCELL * 4);      // memset region start
    size_t oHist = alloc((size_t)NBX * 4);        // contiguous with rcnt
    size_t oRoff = alloc((size_t)NCELL * 4);
    size_t oRpos = alloc((size_t)NCELL * 4);
    size_t oXoff = alloc((size_t)(NBX + 1) * 4);
    size_t oXpos = alloc((size_t)NBX * 4);
    size_t oRpc  = alloc((size_t)M * 16);
    size_t oRpx  = alloc((size_t)M * 16);
    size_t oRix  = alloc((size_t)M * 4);

    if (offb > ws_size || M < KNN) {
        knn_fused<<<(N + 255) / 256, 256, 0, stream>>>(q, r, f, out, N, M);
        return;
    }
    char* ws = (char*)d_ws;
    float*  B    = (float*)(ws + oB);
    int*    rcnt = (int*)(ws + oRcnt);
    int*    hist = (int*)(ws + oHist);
    int*    roff = (int*)(ws + oRoff);
    int*    rpos = (int*)(ws + oRpos);
    int*    xoff = (int*)(ws + oXoff);
    int*    xpos = (int*)(ws + oXpos);
    float4* rpc  = (float4*)(ws + oRpc);
    float4* rpx  = (float4*)(ws + oRpx);
    int*    rixx = (int*)(ws + oRix);

    hipMemsetAsync(ws + oRcnt, 0, (size_t)(NCELL + NBX) * 4 + 32, stream);
    bounds_kern<<<1, 256, 0, stream>>>(r, M, B);
    int gm = (M + 255) / 256;
    count2_kern<<<gm, 256, 0, stream>>>(r, M, B, rcnt, hist);
    prefix_both<<<2, 1024, 0, stream>>>(rcnt, roff, rpos, hist, xoff, xpos);
    scatter2_kern<<<gm, 256, 0, stream>>>(r, M, B, rpos, xpos, rpc, rpx, rixx);
    knn_x<<<(N + 3) / 4, 256, 0, stream>>>(q, f, rpc, roff, rcnt, rpx, rixx, xoff,
                                           B, out, N, M);
}